// Round 1
// baseline (22.796 us; speedup 1.0000x reference)
//
#include <hip/hip_runtime.h>
#include <math.h>

// Gauss2DEffect: per-pixel-sigma horizontal Gaussian blur.
// x:     [1, 3, 1024, 1024] f32
// sigma: [1, 1, 1024, 1024] f32
// out:   [1, 3, 1024, 1024] f32
//
// Because DXDY=(1,0) and taps are integers, bilinear sampling degenerates to
// clamped integer fetches along the row. Weights are symmetric in the tap
// index, and the center tap always survives the half_step gate, so norm >= 1.

#define HH 1024
#define WW 1024
#define CC 3
#define KK 10

__global__ __launch_bounds__(256) void gauss1d_kernel(
    const float* __restrict__ x,
    const float* __restrict__ sigma,
    float* __restrict__ out)
{
    const int idx = blockIdx.x * blockDim.x + threadIdx.x;  // pixel index in [0, H*W)
    if (idx >= HH * WW) return;
    const int h = idx >> 10;       // W == 1024
    const int w = idx & (WW - 1);

    const float sig = sigma[idx];
    const float inv2s2 = 1.0f / (2.0f * sig * sig);
    // half_step = ceil(2*sigma); gate taps with |i| <= half_step (and |i| <= K)
    const float hs = ceilf(2.0f * sig);
    const int hsi = (hs > (float)KK) ? KK : (int)hs;

    float wts[KK + 1];
    wts[0] = 1.0f;
    float norm = 1.0f;
    #pragma unroll
    for (int i = 1; i <= KK; ++i) {
        const float e = __expf(-(float)(i * i) * inv2s2);
        const float wv = (i <= hsi) ? e : 0.0f;
        wts[i] = wv;
        norm += 2.0f * wv;
    }
    const float inv_norm = 1.0f / norm;   // norm >= 1 always (center tap)

    #pragma unroll
    for (int c = 0; c < CC; ++c) {
        const float* __restrict__ rc = x + c * (HH * WW) + h * WW;
        float acc = rc[w] * wts[0];
        #pragma unroll
        for (int i = 1; i <= KK; ++i) {
            int wl = w - i; if (wl < 0) wl = 0;
            int wr = w + i; if (wr > WW - 1) wr = WW - 1;
            acc += wts[i] * (rc[wl] + rc[wr]);
        }
        out[c * (HH * WW) + idx] = acc * inv_norm;
    }
}

extern "C" void kernel_launch(void* const* d_in, const int* in_sizes, int n_in,
                              void* d_out, int out_size, void* d_ws, size_t ws_size,
                              hipStream_t stream) {
    const float* x = (const float*)d_in[0];
    const float* sigma = (const float*)d_in[1];
    float* out = (float*)d_out;

    const int n_pix = HH * WW;
    const int block = 256;
    const int grid = (n_pix + block - 1) / block;
    gauss1d_kernel<<<grid, block, 0, stream>>>(x, sigma, out);
}

// Round 2
// 12.094 us; speedup vs baseline: 1.8848x; 1.8848x over previous
//
#include <hip/hip_runtime.h>
#include <math.h>

// Gauss2DEffect: per-pixel-sigma horizontal Gaussian blur, f32.
// x: [1,3,1024,1024], sigma: [1,1,1024,1024], out: [1,3,1024,1024]
//
// DXDY=(1,0), integer taps -> clamped nearest fetches along the row.
// Each thread computes 4 consecutive pixels from a 28-float register window
// loaded as 7 aligned float4s. Edge clamp is branch-free: since w0 % 4 == 0,
// every float4 of the window is either fully in-bounds or fully clamped, so
// cndmask against rc[0]/rc[1023] fixes the edges.
// Weights: exp(-i^2/(2s^2)) = q^(i^2), q = exp(-1/(2s^2)), built with the
// recurrence w_i = w_{i-1} * q^(2i-1): 1 exp per pixel instead of 10.

#define HH 1024
#define WW 1024
#define CC 3
#define KK 10
#define PP 4   // pixels per thread

__global__ __launch_bounds__(256) void gauss1d_kernel(
    const float* __restrict__ x,
    const float* __restrict__ sigma,
    float* __restrict__ out)
{
    const int t = blockIdx.x * blockDim.x + threadIdx.x;
    const int p0 = t * PP;                 // first pixel of this thread
    const int h = p0 >> 10;                // W == 1024
    const int w0 = p0 & (WW - 1);          // multiple of 4

    // ---- per-pixel weights (4 pixels, 11 taps each, symmetric) ----
    const float4 sg4 = *reinterpret_cast<const float4*>(sigma + p0);
    const float sgs[PP] = {sg4.x, sg4.y, sg4.z, sg4.w};
    float wts[PP][KK + 1];
    float inv_norm[PP];
    #pragma unroll
    for (int p = 0; p < PP; ++p) {
        const float sig = sgs[p];
        const float inv2s2 = __builtin_amdgcn_rcpf(2.0f * sig * sig);
        const float hs = ceilf(2.0f * sig);          // half_step
        const float q = __expf(-inv2s2);             // q = exp(-1/(2s^2))
        const float q2 = q * q;
        float wp = 1.0f;   // gated w_{i-1}
        float tq = q;      // q^(2i-1)
        float norm = 1.0f;
        wts[p][0] = 1.0f;
        #pragma unroll
        for (int i = 1; i <= KK; ++i) {
            float wi = wp * tq;                      // q^(i^2) (0 once gated)
            tq *= q2;
            wi = ((float)i <= hs) ? wi : 0.0f;       // half_step gate
            wts[p][i] = wi;
            norm += 2.0f * wi;
            wp = wi;
        }
        inv_norm[p] = __builtin_amdgcn_rcpf(norm);   // norm >= 1 always
    }

    const int base = w0 - 12;                        // window start (rel row)
    #pragma unroll
    for (int c = 0; c < CC; ++c) {
        const float* __restrict__ rc = x + c * (HH * WW) + h * WW;
        const float left  = rc[0];
        const float right = rc[WW - 1];
        float v[28];
        #pragma unroll
        for (int k = 0; k < 7; ++k) {
            const int bk = base + 4 * k;
            int bkc = bk < 0 ? 0 : bk;
            bkc = bkc > (WW - 4) ? (WW - 4) : bkc;   // keep load in-bounds
            float4 lv = *reinterpret_cast<const float4*>(rc + bkc);
            if (k < 3) {                              // possible left clamp
                const bool cl = bk < 0;               // fully-clamped vector
                lv.x = cl ? left : lv.x;  lv.y = cl ? left : lv.y;
                lv.z = cl ? left : lv.z;  lv.w = cl ? left : lv.w;
            }
            if (k > 3) {                              // possible right clamp
                const bool cr = bk > (WW - 4);
                lv.x = cr ? right : lv.x; lv.y = cr ? right : lv.y;
                lv.z = cr ? right : lv.z; lv.w = cr ? right : lv.w;
            }
            v[4 * k + 0] = lv.x; v[4 * k + 1] = lv.y;
            v[4 * k + 2] = lv.z; v[4 * k + 3] = lv.w;
        }

        float4 res;
        float* rp = reinterpret_cast<float*>(&res);
        #pragma unroll
        for (int p = 0; p < PP; ++p) {
            const int o = 12 + p;                    // center index in window
            float acc = v[o];                        // w0 == 1
            #pragma unroll
            for (int i = 1; i <= KK; ++i)
                acc += wts[p][i] * (v[o - i] + v[o + i]);
            rp[p] = acc * inv_norm[p];
        }
        *reinterpret_cast<float4*>(out + c * (HH * WW) + p0) = res;
    }
}

extern "C" void kernel_launch(void* const* d_in, const int* in_sizes, int n_in,
                              void* d_out, int out_size, void* d_ws, size_t ws_size,
                              hipStream_t stream) {
    const float* x = (const float*)d_in[0];
    const float* sigma = (const float*)d_in[1];
    float* out = (float*)d_out;

    const int n_threads = (HH * WW) / PP;   // 262144
    const int block = 256;
    const int grid = n_threads / block;     // 1024
    gauss1d_kernel<<<grid, block, 0, stream>>>(x, sigma, out);
}